// Round 9
// baseline (270.021 us; speedup 1.0000x reference)
//
#include <hip/hip_runtime.h>
#include <math.h>

// TopKMoEGate via split-bf16 MFMA:
//   x = xh + xl, W = wh + wl (bf16 hi/lo); logits = xh*wh + xh*wl + xl*wh
//   (fp32-accurate to ~5e-6; wave-parallel fp64 tie-guard on top-3 candidates).
// R16: barrier-free register K-loop. Five passing kernels show a convoy cost
//     tied to the per-chunk barrier+drain lockstep (R14: 11.8K cy/iter vs ~4K
//     accountable work); geometry changes inside that structure moved only 5%.
//     This is a skinny-N GEMM (N=64), x-stream-bound (134 MB -> ~21 us floor).
//     So: NO LDS, NO DMA, NO K-loop barriers. Both operands reg-loaded from
//     global. R8 failed this because loads sank to uses (VGPR=48); fix is
//     named sets + asm memory fences pinning issue order (loads cannot cross
//     a fence; WAR reg-deps protect set rotation), giving compiler-counted
//     vmcnt at distance 2 for x (HBM/L3) and 1 for W (L2-resident, 0.5 MB).
//     16 waves = 4 tok-groups x 2 exp-halves x 2 K-halves; wave = 16 tok x
//     32 exp x K1024; grid 256 (1 blk/CU, 4 waves/SIMD). All K-step offsets
//     are compile-time immediates. K-partials combined in 16.6 KB LDS after
//     the loop (2 barriers total), then the proven lane=expert epilogue.

typedef __attribute__((ext_vector_type(8))) __bf16 bf16x8;
typedef __attribute__((ext_vector_type(8))) unsigned short u16x8;
typedef __attribute__((ext_vector_type(4))) float f32x4;
typedef __attribute__((ext_vector_type(4))) unsigned u32x4;

constexpr int EXPN = 64;    // experts
constexpr int TM   = 64;    // tokens per block
constexpr int NS   = 32;    // K-steps per wave (1024 k / 32)

__device__ __forceinline__ void split2(float f, unsigned short& h, unsigned short& l) {
    const unsigned b = __float_as_uint(f);
    h = (unsigned short)(b >> 16);                       // bf16 hi (truncate)
    const float fh = __uint_as_float(b & 0xffff0000u);
    l = (unsigned short)(__float_as_uint(f - fh) >> 16); // bf16 lo
}

__device__ __forceinline__ bf16x8 as_bf16(u16x8 v) {
    union { u16x8 u; bf16x8 b; } c; c.u = v; return c.b;
}
__device__ __forceinline__ bf16x8 as_bf16_u32(u32x4 v) {
    union { u32x4 u; bf16x8 b; } c; c.u = v; return c.b;
}

// perm-packed split2 of 8 fp32 -> bf16 hi/lo vectors (bit-identical to split2)
__device__ __forceinline__ void split_pack(float4 a, float4 c, bf16x8& hi, bf16x8& lo) {
    const unsigned u0=__float_as_uint(a.x), u1=__float_as_uint(a.y),
                   u2=__float_as_uint(a.z), u3=__float_as_uint(a.w),
                   u4=__float_as_uint(c.x), u5=__float_as_uint(c.y),
                   u6=__float_as_uint(c.z), u7=__float_as_uint(c.w);
    u32x4 hp, lp;
    hp[0] = __builtin_amdgcn_perm(u1, u0, 0x07060302u);
    hp[1] = __builtin_amdgcn_perm(u3, u2, 0x07060302u);
    hp[2] = __builtin_amdgcn_perm(u5, u4, 0x07060302u);
    hp[3] = __builtin_amdgcn_perm(u7, u6, 0x07060302u);
    const unsigned d0=__float_as_uint(a.x-__uint_as_float(u0&0xffff0000u));
    const unsigned d1=__float_as_uint(a.y-__uint_as_float(u1&0xffff0000u));
    const unsigned d2=__float_as_uint(a.z-__uint_as_float(u2&0xffff0000u));
    const unsigned d3=__float_as_uint(a.w-__uint_as_float(u3&0xffff0000u));
    const unsigned d4=__float_as_uint(c.x-__uint_as_float(u4&0xffff0000u));
    const unsigned d5=__float_as_uint(c.y-__uint_as_float(u5&0xffff0000u));
    const unsigned d6=__float_as_uint(c.z-__uint_as_float(u6&0xffff0000u));
    const unsigned d7=__float_as_uint(c.w-__uint_as_float(u7&0xffff0000u));
    lp[0] = __builtin_amdgcn_perm(d1, d0, 0x07060302u);
    lp[1] = __builtin_amdgcn_perm(d3, d2, 0x07060302u);
    lp[2] = __builtin_amdgcn_perm(d5, d4, 0x07060302u);
    lp[3] = __builtin_amdgcn_perm(d7, d6, 0x07060302u);
    hi = as_bf16_u32(hp); lo = as_bf16_u32(lp);
}

// ---- pre-kernel: W fp32 -> wh/wl bf16 planes (same split2 numerics) ----
__global__ __launch_bounds__(256)
void convert_w_kernel(const float* __restrict__ W,
                      unsigned short* __restrict__ whp,
                      unsigned short* __restrict__ wlp, int n4)
{
    const int i = blockIdx.x * 256 + threadIdx.x;   // float4 index
    if (i >= n4) return;
    const float4 v = *(const float4*)(W + (size_t)i * 4);
    const float f[4] = {v.x, v.y, v.z, v.w};
    unsigned short h[4], l[4];
#pragma unroll
    for (int j = 0; j < 4; ++j) split2(f[j], h[j], l[j]);
    *(ushort4*)(whp + (size_t)i * 4) = make_ushort4(h[0], h[1], h[2], h[3]);
    *(ushort4*)(wlp + (size_t)i * 4) = make_ushort4(l[0], l[1], l[2], l[3]);
}

#define MFMA16(a, b, c) __builtin_amdgcn_mfma_f32_16x16x32_bf16((a), (b), (c), 0, 0, 0)

__global__ __launch_bounds__(1024, 4)
void moe_gate_kernel(const float* __restrict__ x,      // [M, D]
                     const float* __restrict__ W,      // [E, D] (fp64 guard only)
                     const unsigned short* __restrict__ whp,  // [E, D] bf16 hi
                     const unsigned short* __restrict__ wlp,  // [E, D] bf16 lo
                     const float* __restrict__ nw,     // [E]
                     const float* __restrict__ noise,  // [M, E]
                     float* __restrict__ probs,        // [M, E]
                     float* __restrict__ idx_out,      // [M, 2] float-encoded
                     float* __restrict__ val_out,      // [M, 2]
                     int D)                            // = 2048 (NS*32*2)
{
    __shared__ float ps[TM][EXPN + 1];   // K-half combine + epilogue (16.6 KB)

    const int tid  = threadIdx.x;
    const int lane = tid & 63;
    const int wv   = tid >> 6;          // 0..15
    const int tg   = wv & 3;            // token group (16 tokens)
    const int eh   = (wv >> 2) & 1;     // expert half (32 experts)
    const int kh   = wv >> 3;           // K half (1024 k)
    const int m0   = blockIdx.x * TM;

    const int fr  = lane & 15;          // A row (token) / B row (expert)
    const int khi = lane >> 4;          // k sub-offset = khi*8

    // per-lane fragment base pointers (16B-aligned); step s adds s*128 B (x)
    // or s*64 B (W) -> compile-time immediate offsets for all 32 steps.
    const float* xb = x + (size_t)(m0 + tg * 16 + fr) * D + kh * (D >> 1) + khi * 8;
    const int e0 = eh * 32 + fr, e1 = e0 + 16;
    const unsigned short* w0h = whp + (size_t)e0 * D + kh * (D >> 1) + khi * 8;
    const unsigned short* w0l = wlp + (size_t)e0 * D + kh * (D >> 1) + khi * 8;
    const unsigned short* w1h = whp + (size_t)e1 * D + kh * (D >> 1) + khi * 8;
    const unsigned short* w1l = wlp + (size_t)e1 * D + kh * (D >> 1) + khi * 8;

    f32x4 acc0 = {0.f, 0.f, 0.f, 0.f};  // experts e0 frag
    f32x4 acc1 = {0.f, 0.f, 0.f, 0.f};  // experts e1 frag

    // named register sets: x distance-2 (3 sets), W distance-1 (2 sets)
    float4 X0a, X0b, X1a, X1b, X2a, X2b;
    u16x8  WAh0, WAl0, WAh1, WAl1, WBh0, WBl0, WBh1, WBl1;

#define LOADX(XS, s) {                                                  \
        XS##a = *(const float4*)(xb + (s) * 32);                        \
        XS##b = *(const float4*)(xb + (s) * 32 + 4);                    \
    }
#define LOADW(WS, s) {                                                  \
        WS##h0 = *(const u16x8*)(w0h + (s) * 32);                       \
        WS##l0 = *(const u16x8*)(w0l + (s) * 32);                       \
        WS##h1 = *(const u16x8*)(w1h + (s) * 32);                       \
        WS##l1 = *(const u16x8*)(w1l + (s) * 32);                       \
    }
#define FENCE asm volatile("" ::: "memory");
#define COMPUTE(XS, WS) {                                               \
        bf16x8 ah_, al_;                                                \
        split_pack(XS##a, XS##b, ah_, al_);                             \
        acc0 = MFMA16(ah_, as_bf16(WS##h0), acc0);                      \
        acc0 = MFMA16(ah_, as_bf16(WS##l0), acc0);                      \
        acc0 = MFMA16(al_, as_bf16(WS##h0), acc0);                      \
        acc1 = MFMA16(ah_, as_bf16(WS##h1), acc1);                      \
        acc1 = MFMA16(ah_, as_bf16(WS##l1), acc1);                      \
        acc1 = MFMA16(al_, as_bf16(WS##h1), acc1);                      \
    }
// STEP s: issue W for s+1 and x for s+2 (pinned by FENCE; WAR reg-deps make
// set rotation race-free), then compute step s. Compiler emits counted vmcnt.
#define STEP(s, XC, XN, WC, WN) {                                       \
        if ((s) + 1 < NS) LOADW(WN, (s) + 1)                            \
        if ((s) + 2 < NS) LOADX(XN, (s) + 2)                            \
        FENCE                                                           \
        COMPUTE(XC, WC)                                                 \
    }
#define SIX(s)                                                          \
    STEP((s),     X0, X2, WA, WB)                                       \
    STEP((s) + 1, X1, X0, WB, WA)                                       \
    STEP((s) + 2, X2, X1, WA, WB)                                       \
    STEP((s) + 3, X0, X2, WB, WA)                                       \
    STEP((s) + 4, X1, X0, WA, WB)                                       \
    STEP((s) + 5, X2, X1, WB, WA)

    LOADX(X0, 0)
    LOADX(X1, 1)
    LOADW(WA, 0)
    FENCE

    SIX(0) SIX(6) SIX(12) SIX(18) SIX(24)
    STEP(30, X0, X2, WA, WB)
    STEP(31, X1, X0, WB, WA)

#undef LOADX
#undef LOADW
#undef STEP
#undef SIX
#undef COMPUTE
#undef FENCE

    // ---- combine K halves; C/D layout: col = lane&15, row = (lane>>4)*4+r ----
    const int trow = tg * 16 + khi * 4;
    const int ec   = eh * 32 + fr;
    if (kh == 1) {
#pragma unroll
        for (int r = 0; r < 4; ++r) {
            ps[trow + r][ec]      = acc0[r];
            ps[trow + r][ec + 16] = acc1[r];
        }
    }
    __syncthreads();
    if (kh == 0) {
#pragma unroll
        for (int r = 0; r < 4; ++r) {
            ps[trow + r][ec]      += acc0[r];
            ps[trow + r][ec + 16] += acc1[r];
        }
    }
    __syncthreads();

    // ---- epilogue: per-token noisy top-2 + sparse softmax (lane = expert) ----
    const float nwv = nw[lane];

#pragma unroll 1
    for (int t = 0; t < 4; ++t) {
        const int tl = wv * 4 + t;       // local token (16 waves x 4 = 64)
        const int g  = m0 + tl;          // global token
        const float logit = fmaf(noise[(size_t)g * EXPN + lane], nwv, ps[tl][lane]);

        float v0; int i0;
        {
            float v = logit; int ix = lane;
#pragma unroll
            for (int off = 32; off; off >>= 1) {
                const float vo = __shfl_xor(v, off);
                const int   io = __shfl_xor(ix, off);
                if (vo > v || (vo == v && io < ix)) { v = vo; ix = io; }
            }
            v0 = v; i0 = ix;
        }
        float v1; int i1;
        {
            float v = (lane == i0) ? -INFINITY : logit; int ix = lane;
#pragma unroll
            for (int off = 32; off; off >>= 1) {
                const float vo = __shfl_xor(v, off);
                const int   io = __shfl_xor(ix, off);
                if (vo > v || (vo == v && io < ix)) { v = vo; ix = io; }
            }
            v1 = v; i1 = ix;
        }
        float v2; int i2;
        {
            float v = (lane == i0 || lane == i1) ? -INFINITY : logit; int ix = lane;
#pragma unroll
            for (int off = 32; off; off >>= 1) {
                const float vo = __shfl_xor(v, off);
                const int   io = __shfl_xor(ix, off);
                if (vo > v || (vo == v && io < ix)) { v = vo; ix = io; }
            }
            v2 = v; i2 = ix;
        }

        // near-tie guard: wave-parallel fp64 recompute of the 3 candidate
        // logits (lanes stride K by 64 -> coalesced; butterfly fp64 sum).
        // eps = 1e-3 vs main-path err sigma ~5e-6: ~200-sigma margin (proven).
        const float eps = 1e-3f;
        if ((v0 - v1) < eps || (v1 - v2) < eps) {
            const float* xr  = x + (size_t)g * D;
            const float* w0r = W + (size_t)i0 * D;
            const float* w1r = W + (size_t)i1 * D;
            const float* w2r = W + (size_t)i2 * D;
            double s0 = 0.0, s1 = 0.0, s2 = 0.0;
            for (int d = lane; d < D; d += 64) {
                const double xv = (double)xr[d];
                s0 += xv * (double)w0r[d];
                s1 += xv * (double)w1r[d];
                s2 += xv * (double)w2r[d];
            }
#pragma unroll
            for (int off = 32; off; off >>= 1) {
                s0 += __shfl_xor(s0, off);
                s1 += __shfl_xor(s1, off);
                s2 += __shfl_xor(s2, off);
            }
            double d0 = s0 + (double)noise[(size_t)g * EXPN + i0] * (double)nw[i0];
            double d1 = s1 + (double)noise[(size_t)g * EXPN + i1] * (double)nw[i1];
            double d2 = s2 + (double)noise[(size_t)g * EXPN + i2] * (double)nw[i2];
            // sort 3 (value desc, index asc on ties)
            #define CSWAP(va, ia, vb, ib)                                   \
                if ((vb > va) || (vb == va && ib < ia)) {                   \
                    double tv = va; va = vb; vb = tv;                       \
                    int ti = ia; ia = ib; ib = ti; }
            CSWAP(d0, i0, d1, i1)
            CSWAP(d1, i1, d2, i2)
            CSWAP(d0, i0, d1, i1)
            #undef CSWAP
            v0 = (float)d0; v1 = (float)d1;
        }

        const float e1  = expf(v1 - v0);
        const float inv = 1.0f / (1.0f + e1);

        float p = 0.f;
        if (lane == i0)      p = inv;
        else if (lane == i1) p = e1 * inv;
        probs[(size_t)g * EXPN + lane] = p;

        if (lane == 0) {
            idx_out[(size_t)g * 2 + 0] = (float)i0;
            idx_out[(size_t)g * 2 + 1] = (float)i1;
            val_out[(size_t)g * 2 + 0] = v0;
            val_out[(size_t)g * 2 + 1] = v1;
        }
    }
}

extern "C" void kernel_launch(void* const* d_in, const int* in_sizes, int n_in,
                              void* d_out, int out_size, void* d_ws, size_t ws_size,
                              hipStream_t stream) {
    const float* x     = (const float*)d_in[0];  // [B,S,D]
    const float* W     = (const float*)d_in[1];  // [E,D]
    const float* nw    = (const float*)d_in[2];  // [E]
    const float* noise = (const float*)d_in[3];  // [B,S,E]

    const int M = in_sizes[3] / EXPN;            // 16384 tokens
    const int D = in_sizes[0] / M;               // 2048
    const int wn = in_sizes[1];                  // E*D = 131072

    unsigned short* whp = (unsigned short*)d_ws;            // [E,D] bf16 hi
    unsigned short* wlp = whp + (size_t)wn;                 // [E,D] bf16 lo

    float* probs   = (float*)d_out;              // [M, E]
    float* idx_out = probs + (size_t)M * EXPN;   // [M, 2]
    float* val_out = idx_out + (size_t)M * 2;    // [M, 2]

    const int n4 = wn / 4;
    convert_w_kernel<<<(n4 + 255) / 256, 256, 0, stream>>>(W, whp, wlp, n4);

    const int grid = M / TM;                     // 256 blocks (1 per CU)
    moe_gate_kernel<<<grid, 1024, 0, stream>>>(x, W, whp, wlp, nw, noise,
                                               probs, idx_out, val_out, D);
}